// Round 2
// baseline (101.912 us; speedup 1.0000x reference)
//
#include <hip/hip_runtime.h>
#include <hip/hip_bf16.h>

typedef __attribute__((ext_vector_type(8))) short short8;
typedef __attribute__((ext_vector_type(4))) float f32x4;

#define NB   16
#define TENC 512
#define DCH  256
#define TMEL 4096
#define ROWS (NB*TENC)   // 8192

__device__ __forceinline__ unsigned short f2bf(float f){
  unsigned u = __builtin_bit_cast(unsigned, f);
  u += 0x7FFFu + ((u >> 16) & 1u);
  return (unsigned short)(u >> 16);
}

// ---- cast x to bf16; pack w1/w2 into MFMA B-fragment layout ----
// Wp[ks][nt][lane][j] = W[ks*32 + (lane>>4)*8 + j][nt*16 + (lane&15)]
__global__ void prep_kernel(const float* __restrict__ x,
                            const float* __restrict__ w1,
                            const float* __restrict__ w2,
                            unsigned short* __restrict__ xb,
                            unsigned short* __restrict__ w1p,
                            unsigned short* __restrict__ w2p){
  int i = blockIdx.x * 256 + threadIdx.x;
  if (i < ROWS * DCH) xb[i] = f2bf(x[i]);
  if (i < 24 * 16 * 64 * 8){
    int j    = i & 7;
    int lane = (i >> 3) & 63;
    int nt   = (i >> 9) & 15;
    int ks   = i >> 13;
    int r    = ks * 32 + ((lane >> 4) * 8) + j;
    int col  = nt * 16 + (lane & 15);
    w1p[i] = f2bf(w1[r * 256 + col]);
    w2p[i] = f2bf(w2[r * 256 + col]);
  }
}

// ---- per-batch inclusive cumsum of target ----
__global__ void scan_kernel(const int* __restrict__ target,
                            int* __restrict__ cum, int* __restrict__ total){
  __shared__ int s[512];
  int b = blockIdx.x, tid = threadIdx.x;
  s[tid] = target[b * 512 + tid];
  __syncthreads();
  for (int off = 1; off < 512; off <<= 1){
    int v = (tid >= off) ? s[tid - off] : 0;
    __syncthreads();
    s[tid] += v;
    __syncthreads();
  }
  cum[b * 512 + tid] = s[tid];
  if (tid == 511) total[b] = s[511];
}

// ---- length regulator: 4 waves/block, one (b,t_mel) row per wave.
// Writes output row (f32 gather) AND full alignment row (zeros + one 1.0f).
__global__ __launch_bounds__(256) void lr_kernel(const float* __restrict__ x,
    const int* __restrict__ cum, const int* __restrict__ total,
    float* __restrict__ out0, float* __restrict__ alignp){
  int row  = blockIdx.x * 4 + (threadIdx.x >> 6);
  int lane = threadIdx.x & 63;
  int b = row >> 12, t = row & 4095;
  size_t orow = (size_t)row * 256;
  size_t arow = (size_t)row * 512;
  int tot = total[b];
  float4 z = {0.f, 0.f, 0.f, 0.f};
  if (t >= tot){
    *reinterpret_cast<float4*>(out0 + orow + lane * 4) = z;
    *reinterpret_cast<float4*>(alignp + arow + lane * 8) = z;
    *reinterpret_cast<float4*>(alignp + arow + lane * 8 + 4) = z;
    return;
  }
  const int* cb = cum + b * 512;
  int lo = 0, hi = 511;
  while (lo < hi){ int mid = (lo + hi) >> 1; if (cb[mid] > t) hi = mid; else lo = mid + 1; }
  const float4 v = *reinterpret_cast<const float4*>(x + ((size_t)b * TENC + lo) * DCH + lane * 4);
  *reinterpret_cast<float4*>(out0 + orow + lane * 4) = v;
  float4 a0 = z, a1 = z;
  int rel = lo - lane * 8;
  if (rel >= 0 && rel < 8){
    if (rel < 4) (&a0.x)[rel] = 1.0f; else (&a1.x)[rel - 4] = 1.0f;
  }
  *reinterpret_cast<float4*>(alignp + arow + lane * 8) = a0;
  *reinterpret_cast<float4*>(alignp + arow + lane * 8 + 4) = a1;
}

// ---- conv1d(K=3,SAME) as GEMM [16 x 256] = X3[16 x 768] @ W[768 x 256],
//      fused bias + LayerNorm + relu; either stores h (bf16) or does
//      the final dot with wl + exp -> dur (f32). 4 waves, 16x64 each.
__global__ __launch_bounds__(256) void conv_ln_kernel(
    const unsigned short* __restrict__ inb,   // [8192][256] bf16
    const unsigned short* __restrict__ wp,    // packed weights
    const float* __restrict__ bias,
    const float* __restrict__ gamma,
    const float* __restrict__ beta,
    unsigned short* __restrict__ outb,        // h out, or nullptr
    const float* __restrict__ wl,
    const float* __restrict__ blp,
    float* __restrict__ dur)
{
  __shared__ float red[16][4][2];
  __shared__ float dred[16][4];
  int m0 = blockIdx.x * 16;
  int tid = threadIdx.x;
  int wave = tid >> 6, l = tid & 63;
  int kgrp = l >> 4;                 // 0..3
  int t = m0 + (l & 15);             // A-operand row (global)
  int tl = t & 511;                  // row within batch
  f32x4 acc[4];
  #pragma unroll
  for (int i = 0; i < 4; ++i) acc[i] = (f32x4)0.0f;

  for (int ks = 0; ks < 24; ++ks){
    int shift = ks >> 3;                       // which of the 3 taps
    int c = (ks & 7) * 32 + kgrp * 8;          // channel offset
    short8 a = {0,0,0,0,0,0,0,0};
    if ((unsigned)(tl + shift - 1) < 512u)
      a = *reinterpret_cast<const short8*>(inb + (size_t)(t + shift - 1) * DCH + c);
    const unsigned short* wb = wp + (size_t)(ks * 16 + wave * 4) * 512 + l * 8;
    short8 b0 = *reinterpret_cast<const short8*>(wb);
    short8 b1 = *reinterpret_cast<const short8*>(wb + 512);
    short8 b2 = *reinterpret_cast<const short8*>(wb + 1024);
    short8 b3 = *reinterpret_cast<const short8*>(wb + 1536);
    acc[0] = __builtin_amdgcn_mfma_f32_16x16x32_bf16(a, b0, acc[0], 0, 0, 0);
    acc[1] = __builtin_amdgcn_mfma_f32_16x16x32_bf16(a, b1, acc[1], 0, 0, 0);
    acc[2] = __builtin_amdgcn_mfma_f32_16x16x32_bf16(a, b2, acc[2], 0, 0, 0);
    acc[3] = __builtin_amdgcn_mfma_f32_16x16x32_bf16(a, b3, acc[3], 0, 0, 0);
  }

  // bias + per-row sum / sum-of-squares (C/D layout: col=lane&15, row=kgrp*4+q)
  int colbase = wave * 64 + (l & 15);
  float s1[4] = {0,0,0,0}, s2[4] = {0,0,0,0};
  #pragma unroll
  for (int nt = 0; nt < 4; ++nt){
    float bv = bias[colbase + nt * 16];
    #pragma unroll
    for (int q = 0; q < 4; ++q){
      float v = acc[nt][q] + bv;
      acc[nt][q] = v;
      s1[q] += v; s2[q] += v * v;
    }
  }
  #pragma unroll
  for (int m = 1; m < 16; m <<= 1){
    #pragma unroll
    for (int q = 0; q < 4; ++q){
      s1[q] += __shfl_xor(s1[q], m);
      s2[q] += __shfl_xor(s2[q], m);
    }
  }
  if ((l & 15) == 0){
    #pragma unroll
    for (int q = 0; q < 4; ++q){
      red[kgrp * 4 + q][wave][0] = s1[q];
      red[kgrp * 4 + q][wave][1] = s2[q];
    }
  }
  __syncthreads();
  float mu[4], rs[4];
  #pragma unroll
  for (int q = 0; q < 4; ++q){
    int r = kgrp * 4 + q;
    float S1 = red[r][0][0] + red[r][1][0] + red[r][2][0] + red[r][3][0];
    float S2 = red[r][0][1] + red[r][1][1] + red[r][2][1] + red[r][3][1];
    float m_ = S1 * (1.0f / 256.0f);
    float var = S2 * (1.0f / 256.0f) - m_ * m_;
    mu[q] = m_;
    rs[q] = rsqrtf(var + 1e-5f);
  }

  if (outb){
    #pragma unroll
    for (int nt = 0; nt < 4; ++nt){
      int col = colbase + nt * 16;
      float g = gamma[col], be = beta[col];
      #pragma unroll
      for (int q = 0; q < 4; ++q){
        int r = kgrp * 4 + q;
        float y = (acc[nt][q] - mu[q]) * rs[q] * g + be;
        y = fmaxf(y, 0.0f);
        outb[(size_t)(m0 + r) * DCH + col] = f2bf(y);
      }
    }
  } else {
    float dp[4] = {0,0,0,0};
    #pragma unroll
    for (int nt = 0; nt < 4; ++nt){
      int col = colbase + nt * 16;
      float g = gamma[col], be = beta[col], wv = wl[col];
      #pragma unroll
      for (int q = 0; q < 4; ++q){
        float y = (acc[nt][q] - mu[q]) * rs[q] * g + be;
        y = fmaxf(y, 0.0f);
        dp[q] += y * wv;
      }
    }
    #pragma unroll
    for (int m = 1; m < 16; m <<= 1){
      #pragma unroll
      for (int q = 0; q < 4; ++q) dp[q] += __shfl_xor(dp[q], m);
    }
    if ((l & 15) == 0){
      #pragma unroll
      for (int q = 0; q < 4; ++q) dred[kgrp * 4 + q][wave] = dp[q];
    }
    __syncthreads();
    if (tid < 16){
      float d = dred[tid][0] + dred[tid][1] + dred[tid][2] + dred[tid][3] + blp[0];
      dur[m0 + tid] = expf(d);
    }
  }
}

extern "C" void kernel_launch(void* const* d_in, const int* in_sizes, int n_in,
                              void* d_out, int out_size, void* d_ws, size_t ws_size,
                              hipStream_t stream){
  const float* x   = (const float*)d_in[0];
  const int*   target = (const int*)d_in[1];
  const float* w1  = (const float*)d_in[2];
  const float* b1  = (const float*)d_in[3];
  const float* g1  = (const float*)d_in[4];
  const float* be1 = (const float*)d_in[5];
  const float* w2  = (const float*)d_in[6];
  const float* b2  = (const float*)d_in[7];
  const float* g2  = (const float*)d_in[8];
  const float* be2 = (const float*)d_in[9];
  const float* wl  = (const float*)d_in[10];
  const float* bl  = (const float*)d_in[11];

  float* out0   = (float*)d_out;
  float* alignp = out0 + (size_t)NB * TMEL * DCH;     // +16,777,216 f32
  float* durp   = alignp + (size_t)NB * TMEL * TENC;  // +33,554,432 f32

  char* ws = (char*)d_ws;
  int* cum   = (int*)ws;                                        // 32 KB
  int* total = (int*)(ws + 32768);
  unsigned short* xb  = (unsigned short*)(ws + 65536);                    // 4 MB
  unsigned short* w1p = (unsigned short*)(ws + 65536 + 4194304);          // 384 KB
  unsigned short* w2p = (unsigned short*)(ws + 65536 + 4194304 + 393216); // 384 KB
  unsigned short* h1  = (unsigned short*)(ws + 65536 + 4194304 + 786432); // 4 MB

  prep_kernel<<<8192, 256, 0, stream>>>(x, w1, w2, xb, w1p, w2p);
  scan_kernel<<<NB, 512, 0, stream>>>(target, cum, total);
  lr_kernel<<<NB * TMEL / 4, 256, 0, stream>>>(x, cum, total, out0, alignp);
  conv_ln_kernel<<<ROWS / 16, 256, 0, stream>>>(xb, w1p, b1, g1, be1, h1, nullptr, nullptr, nullptr);
  conv_ln_kernel<<<ROWS / 16, 256, 0, stream>>>(h1, w2p, b2, g2, be2, nullptr, wl, bl, durp);
}